// Round 10
// baseline (482.296 us; speedup 1.0000x reference)
//
#include <hip/hip_runtime.h>
#include <hip/hip_bf16.h>

// GlobalAttn: x = lrelu(concat(q,k) @ w1^T + b1); attn[e,h] = x[e,h,:]·w2[h,:];
// out = segment_softmax(attn, index). E=320000, D=256, K=512, H=4, N=10000.
//
// R10: independent-wave GEMM with REGISTER-FORCED pipeline depth.
// Evidence: R8 (same skeleton) was register-starved (VGPR_Count=56 under a
// 128-total cap incl. AGPR) -> compiler serialized A-loads into ~4 x 900cy
// waits/step. Barrier variants (R2/R9) drain the vmem queue every step.
// Fix: no LDS, no barriers, no waits anywhere; launch_bounds(256,2) gives a
// 256-reg budget; explicit ring buffers ar[3][8] (A, prefetch distance 2)
// and br[2][4] (B, distance 1) force ~16 KB/wave in flight via liveness.
// 8 waves/CU x 16 KB = 128 KB/CU in flight >> BW*latency (~20 KB) -> HBM-BW
// bound by construction.
//  * Block 256 thr = 4 waves = 4 heads; wave tile 64x64; BM=64; grid 5000.
//  * A frags read DIRECT from global fp32 (R8-proven layout: lane l reads
//    row l&15, k=(l>>4)*8; 2 float4 per 16-row frag) -> cvt to bf16 in regs.
//  * B from frag-ordered wf table (R8-proven): one coalesced 16B/lane load
//    per fragment, L2-resident (256 KB).
//  * acc[4][4]=64 + ar 96 + br 32 + misc ~40 ≈ 235 <= 256: NO spill
//    (validate: VGPR_Count ~200-256, WRITE_SIZE ~43 MB).

typedef __attribute__((ext_vector_type(8))) short bf16x8;
typedef __attribute__((ext_vector_type(4))) float f32x4;

#define NNODES 10000

__device__ __forceinline__ short f2bf(float f) {
    __hip_bfloat16 h = __float2bfloat16(f);   // RNE
    return *reinterpret_cast<short*>(&h);
}

// ---- B prep: fragment-ordered bf16 (one-time, tiny) ----
// frag id f = c*16 + s (c: 16-col block 0..15, s: 32-k slice 0..15).
// wf[(f*64 + lane)*8 + j] = bf16( w1[c*16 + (lane&15)][s*32 + (lane>>4)*8 + j] )
__global__ void w1_frag(const float* __restrict__ w1, short* __restrict__ wf) {
    int bid = blockIdx.x;            // 0..255 = c*16 + s
    int l   = threadIdx.x;           // 0..63
    int n = (bid >> 4) * 16 + (l & 15);
    int k = (bid & 15) * 32 + (l >> 4) * 8;
    const float* src = w1 + (size_t)n * 512 + k;
    float4 v0 = *(const float4*)src;
    float4 v1 = *(const float4*)(src + 4);
    bf16x8 pk;
    pk[0]=f2bf(v0.x); pk[1]=f2bf(v0.y); pk[2]=f2bf(v0.z); pk[3]=f2bf(v0.w);
    pk[4]=f2bf(v1.x); pk[5]=f2bf(v1.y); pk[6]=f2bf(v1.z); pk[7]=f2bf(v1.w);
    *(bf16x8*)(wf + ((size_t)bid * 64 + l) * 8) = pk;
}

__global__ void seg_init(float* __restrict__ segsum, int n) {
    int i = blockIdx.x * blockDim.x + threadIdx.x;
    if (i < n) segsum[i] = 0.f;
}

// ---------------- main fused GEMM + epilogue ----------------
__global__ __launch_bounds__(256, 2) void attn_gemm(
    const float* __restrict__ q, const float* __restrict__ kk_,
    const short* __restrict__ wf, const float* __restrict__ b1,
    const float* __restrict__ w2, const int* __restrict__ index,
    float* __restrict__ attn, float* __restrict__ segsum)
{
    const int tid  = threadIdx.x;
    const int lane = tid & 63;
    const int hd   = tid >> 6;        // wave = head 0..3
    const int l15  = lane & 15;
    const int lhi  = lane >> 4;
    const int row0 = blockIdx.x * 64; // 5000 blocks

    f32x4 acc[4][4];
#pragma unroll
    for (int i = 0; i < 4; ++i)
#pragma unroll
        for (int j = 0; j < 4; ++j) acc[i][j] = (f32x4){0.f, 0.f, 0.f, 0.f};

    // A base: lane-invariant part (floats); frag fm adds fm*16*256; step adds (s&7)*32
    const size_t abase = (size_t)(row0 + l15) * 256 + lhi * 8;
    // B base: frag (hd*4+fn)*16 + s, 512 shorts each
    const short* wfb = wf + (size_t)(hd * 64) * 512 + lane * 8;

    float4 ar[3][8];   // A ring: step S in slot S%3 (8 float4 = one 64x32 A tile)
    bf16x8 br[2][4];   // B ring: step S in set S&1

#define LOADA(slot, S) {                                                        \
        const float* bp = ((S) < 8) ? q : kk_;                                  \
        const float* p  = bp + abase + ((S) & 7) * 32;                          \
        _Pragma("unroll")                                                       \
        for (int fm = 0; fm < 4; ++fm) {                                        \
            ar[slot][2*fm]   = *(const float4*)(p + fm * 4096);                 \
            ar[slot][2*fm+1] = *(const float4*)(p + fm * 4096 + 4);             \
        }                                                                       \
    }
#define LOADB(set, S) {                                                         \
        _Pragma("unroll")                                                       \
        for (int fn = 0; fn < 4; ++fn)                                          \
            br[set][fn] = *(const bf16x8*)(wfb + (fn * 16 + (S)) * 512);        \
    }

    // ---- prologue: A steps 0,1 in flight; B step 0 in flight ----
    LOADA(0, 0);
    LOADA(1, 1);
    LOADB(0, 0);

    // ---- 16 steps, fully unrolled, zero barriers/waits ----
#pragma unroll
    for (int s = 0; s < 16; ++s) {
        if (s < 15) LOADB((s + 1) & 1, s + 1);
        if (s < 14) LOADA((s + 2) % 3, s + 2);
        __builtin_amdgcn_sched_barrier(0);   // don't sink loads below compute

        bf16x8 af[4];
#pragma unroll
        for (int fm = 0; fm < 4; ++fm) {
            float4 v0 = ar[s % 3][2*fm], v1 = ar[s % 3][2*fm+1];
            bf16x8 pk;
            pk[0]=f2bf(v0.x); pk[1]=f2bf(v0.y); pk[2]=f2bf(v0.z); pk[3]=f2bf(v0.w);
            pk[4]=f2bf(v1.x); pk[5]=f2bf(v1.y); pk[6]=f2bf(v1.z); pk[7]=f2bf(v1.w);
            af[fm] = pk;
        }
#pragma unroll
        for (int fm = 0; fm < 4; ++fm)
#pragma unroll
            for (int fn = 0; fn < 4; ++fn)
                acc[fm][fn] = __builtin_amdgcn_mfma_f32_16x16x32_bf16(
                    af[fm], br[s & 1][fn], acc[fm][fn], 0, 0, 0);
    }
#undef LOADA
#undef LOADB

    // ---- epilogue: bias + lrelu + dot(w2) + exp + atomicAdd(segsum) ----
    float bias[4], w2v[4];
#pragma unroll
    for (int fn = 0; fn < 4; ++fn) {
        int col = hd * 64 + fn * 16 + l15;
        bias[fn] = b1[col];
        w2v[fn]  = w2[col];
    }
#pragma unroll
    for (int fm = 0; fm < 4; ++fm) {
#pragma unroll
        for (int r = 0; r < 4; ++r) {
            int row = row0 + fm * 16 + lhi * 4 + r;   // C/D: row=(l>>4)*4+reg
            float p = 0.f;
#pragma unroll
            for (int fn = 0; fn < 4; ++fn) {
                float y = acc[fm][fn][r] + bias[fn];
                y = (y > 0.f) ? y : 0.01f * y;
                p += y * w2v[fn];
            }
#pragma unroll
            for (int m = 1; m < 16; m <<= 1) p += __shfl_xor(p, m);
            if (l15 == 0) {
                float e = __expf(p);
                attn[(size_t)row * 4 + hd] = e;
                atomicAdd(&segsum[index[row] * 4 + hd], e);
            }
        }
    }
}

__global__ void seg_norm(const float* __restrict__ attn, const int* __restrict__ index,
                         const float* __restrict__ segsum, float* __restrict__ out, int total) {
    int i = blockIdx.x * blockDim.x + threadIdx.x;
    if (i >= total) return;
    int e = i >> 2, h = i & 3;
    out[i] = attn[i] / (segsum[index[e] * 4 + h] + 1e-16f);
}

extern "C" void kernel_launch(void* const* d_in, const int* in_sizes, int n_in,
                              void* d_out, int out_size, void* d_ws, size_t ws_size,
                              hipStream_t stream) {
    const float* q   = (const float*)d_in[0];
    const float* k   = (const float*)d_in[1];
    const float* w1  = (const float*)d_in[2];
    const float* b1  = (const float*)d_in[3];
    const float* w2  = (const float*)d_in[4];
    const int* index = (const int*)d_in[5];

    const int nE = in_sizes[0] / 256;      // 320000
    char* ws = (char*)d_ws;
    float* attn   = (float*)ws;            ws += (size_t)nE * 4 * 4;
    float* segsum = (float*)ws;            ws += (size_t)NNODES * 4 * 4;
    short* wf     = (short*)ws;            // 256*512 bf16 = 256KB, frag-ordered
    float* out    = (float*)d_out;

    w1_frag<<<256, 64, 0, stream>>>(w1, wf);
    seg_init<<<(NNODES * 4 + 255) / 256, 256, 0, stream>>>(segsum, NNODES * 4);

    attn_gemm<<<nE / 64, 256, 0, stream>>>(q, k, wf, b1, w2, index, attn, segsum);

    int total = nE * 4;
    seg_norm<<<(total + 255) / 256, 256, 0, stream>>>(attn, index, segsum, out, total);
}